// Round 1
// baseline (761.757 us; speedup 1.0000x reference)
//
#include <hip/hip_runtime.h>
#include <hip/hip_bf16.h>
#include <cstdint>
#include <cstddef>

// Problem constants (from reference): x[512,4096] fp32, gate/up codes [11008,4096] i32,
// down codes [4096,11008] i32, absmax blocks of 64, out [512,4096] fp32.
#define TOKENS 512

using float4v = __attribute__((ext_vector_type(4))) float;
using short8  = __attribute__((ext_vector_type(8))) short;

__constant__ float NF4TAB[16] = {
  -1.0f, -0.6961928009986877f, -0.5250730514526367f, -0.39491748809814453f,
  -0.28444138169288635f, -0.18477343022823334f, -0.09105003625154495f, 0.0f,
  0.07958029955625534f, 0.16093020141124725f, 0.24611230194568634f,
  0.33791524171829224f, 0.44070982933044434f, 0.5626170039176941f,
  0.7229568362236023f, 1.0f };

__device__ __forceinline__ unsigned short f2bf(float f) {
  unsigned u = __float_as_uint(f);
  u += 0x7fffu + ((u >> 16) & 1u);        // round-to-nearest-even
  return (unsigned short)(u >> 16);
}
__device__ __forceinline__ float bf2f(unsigned short b) {
  return __uint_as_float(((unsigned)b) << 16);
}

__device__ __forceinline__ void async16(const void* g, void* l) {
  __builtin_amdgcn_global_load_lds(
      (const __attribute__((address_space(1))) void*)g,
      (__attribute__((address_space(3))) void*)l, 16, 0, 0);
}

// C[Mrows x N] = A[Mrows x K](bf16) * dequant(codes[N x K])^T
// Block tile: 256(M) x 64(N), BK=64, 4 waves, wave tile 64x64 via 16x16x32 MFMA.
// EPI 0: store bf16 C to outB.   EPI 1: h = silu(gIn) * C -> bf16 outB.
// EPI 2: atomicAdd fp32 into outF (split-K).
template <int EPI>
__global__ __launch_bounds__(256) void gemm_nf4(
    const unsigned short* __restrict__ A,
    const int* __restrict__ codes,
    const float* __restrict__ absmax,
    float* __restrict__ outF,
    unsigned short* __restrict__ outB,
    const unsigned short* __restrict__ gIn,
    int N, int K, int Kc, int Mtiles, int Ntiles)
{
  __shared__ unsigned short Abuf[256 * 64];   // 32 KB, XOR-swizzled 16B chunks per 128B row
  __shared__ unsigned short Bbuf[64 * 72];    // 9 KB, +8 bf16 row pad
  __shared__ float tab[16];                   // one word per bank 0..15 -> broadcast reads

  const int tid  = threadIdx.x;
  const int lane = tid & 63;
  const int wave = tid >> 6;

  if (tid < 16) tab[tid] = NF4TAB[tid];

  const int bid = blockIdx.x;
  const int mt  = bid % Mtiles;
  const int r1  = bid / Mtiles;
  const int nt  = r1 % Ntiles;
  const int ks  = r1 / Ntiles;

  const int row0 = mt * 256;
  const int col0 = nt * 64;
  const int k0   = ks * Kc;
  const int nk   = Kc >> 6;

  // ---- A async staging setup: wave w stages row-groups gidx = j*4+w (8 rows each)
  const int arow = lane >> 3;               // 0..7 row within group
  const int achk = (lane & 7) ^ arow;       // logical 16B chunk for XOR-swizzled store
  const unsigned short* aSrc0 =
      A + (size_t)(row0 + wave * 8 + arow) * K + k0 + achk * 8;

  // ---- B dequant staging setup: thread -> (row bn, quarter bq)
  const int bn = tid >> 2;                  // 0..63 local n
  const int bq = tid & 3;
  const int* cSrc = codes + (size_t)(col0 + bn) * K + k0;
  const float* amSrc = absmax + (size_t)(col0 + bn) * (K >> 6) + (k0 >> 6);

  float4v acc[4][4];
  {
    float4v z = {0.f, 0.f, 0.f, 0.f};
    #pragma unroll
    for (int i = 0; i < 4; ++i)
      #pragma unroll
      for (int j = 0; j < 4; ++j) acc[i][j] = z;
  }

  __syncthreads();   // tab visible

  for (int kt = 0; kt < nk; ++kt) {
    // stage A (async, 8 x 1KB per wave)
    #pragma unroll
    for (int j = 0; j < 8; ++j) {
      async16(aSrc0 + (size_t)j * 32 * K + kt * 64,
              &Abuf[(j * 4 + wave) * 512]);
    }
    // stage B: load 16 codes, dequant, write bf16
    const float am = amSrc[kt];
    #pragma unroll
    for (int i = 0; i < 4; ++i) {
      int4 c4 = ((const int4*)(cSrc + kt * 64))[i * 4 + bq];   // codes k = 16i+4bq..+3
      ushort4 w;
      w.x = f2bf(tab[c4.x] * am);
      w.y = f2bf(tab[c4.y] * am);
      w.z = f2bf(tab[c4.z] * am);
      w.w = f2bf(tab[c4.w] * am);
      *(ushort4*)&Bbuf[bn * 72 + i * 16 + bq * 4] = w;
    }
    __syncthreads();

    // compute: 2 k-steps x 4x4 MFMA
    #pragma unroll
    for (int kk = 0; kk < 2; ++kk) {
      short8 af[4], bfr[4];
      #pragma unroll
      for (int i = 0; i < 4; ++i) {
        const int row_l = wave * 64 + i * 16 + (lane & 15);
        const int gl    = kk * 4 + (lane >> 4);
        const int phys  = gl ^ (lane & 7);          // row_l & 7 == lane & 7
        af[i] = *(const short8*)&Abuf[row_l * 64 + phys * 8];
      }
      #pragma unroll
      for (int j = 0; j < 4; ++j) {
        const int n_l = j * 16 + (lane & 15);
        bfr[j] = *(const short8*)&Bbuf[n_l * 72 + kk * 32 + (lane >> 4) * 8];
      }
      #pragma unroll
      for (int i = 0; i < 4; ++i)
        #pragma unroll
        for (int j = 0; j < 4; ++j)
          acc[i][j] = __builtin_amdgcn_mfma_f32_16x16x32_bf16(af[i], bfr[j], acc[i][j], 0, 0, 0);
    }
    __syncthreads();
  }

  // ---- epilogue. C/D map (verified): col = lane&15, row = (lane>>4)*4 + reg
  const int ccol  = col0 + (lane & 15);
  const int crow0 = row0 + wave * 64 + ((lane >> 4) << 2);
  #pragma unroll
  for (int i = 0; i < 4; ++i) {
    #pragma unroll
    for (int j = 0; j < 4; ++j) {
      #pragma unroll
      for (int r = 0; r < 4; ++r) {
        const size_t idx = (size_t)(crow0 + i * 16 + r) * N + (ccol + j * 16);
        if (EPI == 2) {
          atomicAdd(&outF[idx], acc[i][j][r]);
        } else if (EPI == 0) {
          outB[idx] = f2bf(acc[i][j][r]);
        } else {
          const float gv = bf2f(gIn[idx]);
          const float s  = gv / (1.f + __expf(-gv));   // silu(g)
          outB[idx] = f2bf(s * acc[i][j][r]);
        }
      }
    }
  }
}

__global__ void cast_bf16_kernel(const float* __restrict__ x,
                                 unsigned short* __restrict__ xb, int n4) {
  int i = blockIdx.x * blockDim.x + threadIdx.x;
  if (i < n4) {
    float4 v = ((const float4*)x)[i];
    ushort4 o;
    o.x = f2bf(v.x); o.y = f2bf(v.y); o.z = f2bf(v.z); o.w = f2bf(v.w);
    ((ushort4*)xb)[i] = o;
  }
}

extern "C" void kernel_launch(void* const* d_in, const int* in_sizes, int n_in,
                              void* d_out, int out_size, void* d_ws, size_t ws_size,
                              hipStream_t stream)
{
  (void)in_sizes; (void)n_in; (void)ws_size;
  const float* x            = (const float*)d_in[0];
  const int*   gate_codes   = (const int*)d_in[1];
  const float* gate_absmax  = (const float*)d_in[2];
  const int*   up_codes     = (const int*)d_in[3];
  const float* up_absmax    = (const float*)d_in[4];
  const int*   down_codes   = (const int*)d_in[5];
  const float* down_absmax  = (const float*)d_in[6];
  float* out = (float*)d_out;

  // workspace layout (bf16): xb [512*4096] | g [512*11008] | h [512*11008]  (~27 MB)
  unsigned short* xb = (unsigned short*)d_ws;
  unsigned short* g  = xb + (size_t)512 * 4096;
  unsigned short* h  = g  + (size_t)512 * 11008;

  hipMemsetAsync(d_out, 0, (size_t)out_size * sizeof(float), stream);

  cast_bf16_kernel<<<2048, 256, 0, stream>>>(x, xb, (512 * 4096) / 4);

  // gate: C[512,11008] -> g (bf16).  grid = Mtiles(2) * Ntiles(172)
  gemm_nf4<0><<<344, 256, 0, stream>>>(xb, gate_codes, gate_absmax,
                                       nullptr, g, nullptr,
                                       11008, 4096, 4096, 2, 172);
  // up + fused SwiGLU epilogue: h = silu(g) * u
  gemm_nf4<1><<<344, 256, 0, stream>>>(xb, up_codes, up_absmax,
                                       nullptr, h, g,
                                       11008, 4096, 4096, 2, 172);
  // down: out[512,4096] += h * Wd^T, split-K=4.  grid = 2 * 64 * 4
  gemm_nf4<2><<<512, 256, 0, stream>>>(h, down_codes, down_absmax,
                                       out, nullptr, nullptr,
                                       4096, 11008, 2752, 2, 64);
}